// Round 1
// baseline (1022.446 us; speedup 1.0000x reference)
//
#include <hip/hip_runtime.h>
#include <cstdint>
#include <cstddef>

// ---------------------------------------------------------------------------
// SSTAFormer fused implementation, round 1 (correctness-first MFMA design)
//   graph = 16384 independent blocks of 16 nodes; wave <-> graph mapping.
// ---------------------------------------------------------------------------

typedef __attribute__((ext_vector_type(8))) __bf16 bf16x8;
typedef __attribute__((ext_vector_type(4))) float  f32x4;

#define MFMA16(a,b,c) __builtin_amdgcn_mfma_f32_16x16x32_bf16((a),(b),(c),0,0,0)

#define NGR    16384          // graphs (B)
#define NNODE  262144         // total nodes
#define EDGES  1048576        // total edges
#define PRED_ELEMS (16*16384*24)

// workspace layout, in ushort (bf16) units
#define O_W1L 0               // [128][192]
#define O_W1R 24576
#define O_W2L 49152           // [128][128]
#define O_W2R 65536
#define O_W3L 81920           // [64][128]
#define O_W3R 90112
#define O_T0  98304           // [64 co][64 ci]  (tcn_w[...,0])
#define O_T1  102400
#define O_WQ  106496          // [64][64]
#define O_WK  110592
#define O_WV  114688
#define O_WO  118784
#define O_FC1 122880          // 16 x [64][128]
#define O_FC2 253952          // 16 x [32][64]  (cols>=24 zero)
#define O_FEAT 286720         // [16384][128] bf16
#define PREP_TOT 286720

static __device__ __forceinline__ unsigned short f2bf(float f){
  unsigned int u = __builtin_bit_cast(unsigned int, f);
  u += 0x7FFFu + ((u >> 16) & 1u);            // RNE
  return (unsigned short)(u >> 16);
}
static __device__ __forceinline__ float bf2f(unsigned short h){
  return __builtin_bit_cast(float, (unsigned int)h << 16);
}
static __device__ __forceinline__ bf16x8 ld8(const unsigned short* p){
  return __builtin_bit_cast(bf16x8, *(const uint4*)p);   // 16B aligned by construction
}
static __device__ __forceinline__ void unpack8(const unsigned short* p, float* f){
  uint4 v = *(const uint4*)p;
  unsigned int a0=v.x,a1=v.y,a2=v.z,a3=v.w;
  f[0]=__builtin_bit_cast(float, a0<<16); f[1]=__builtin_bit_cast(float, a0&0xFFFF0000u);
  f[2]=__builtin_bit_cast(float, a1<<16); f[3]=__builtin_bit_cast(float, a1&0xFFFF0000u);
  f[4]=__builtin_bit_cast(float, a2<<16); f[5]=__builtin_bit_cast(float, a2&0xFFFF0000u);
  f[6]=__builtin_bit_cast(float, a3<<16); f[7]=__builtin_bit_cast(float, a3&0xFFFF0000u);
}

// ---------------------------------------------------------------------------
// weight prep: fp32 -> bf16, transposed to [N][K] so B-frags are 16B loads
// ---------------------------------------------------------------------------
__global__ __launch_bounds__(256) void k_prep(
  const float* __restrict__ w1l, const float* __restrict__ w1r,
  const float* __restrict__ w2l, const float* __restrict__ w2r,
  const float* __restrict__ w3l, const float* __restrict__ w3r,
  const float* __restrict__ tcnw,
  const float* __restrict__ wq, const float* __restrict__ wk,
  const float* __restrict__ wv, const float* __restrict__ wo,
  const float* __restrict__ fc1w, const float* __restrict__ fc2w,
  unsigned short* __restrict__ W)
{
  int idx = blockIdx.x*256 + threadIdx.x;
  if (idx >= PREP_TOT) return;
  float v;
  if      (idx <  24576){ int t=idx;        int n=t/192,k=t%192; v=(k<168)? w1l[k*128+n]:0.f; }
  else if (idx <  49152){ int t=idx- 24576; int n=t/192,k=t%192; v=(k<168)? w1r[k*128+n]:0.f; }
  else if (idx <  65536){ int t=idx- 49152; int n=t/128,k=t%128; v=w2l[k*128+n]; }
  else if (idx <  81920){ int t=idx- 65536; int n=t/128,k=t%128; v=w2r[k*128+n]; }
  else if (idx <  90112){ int t=idx- 81920; int n=t/128,k=t%128; v=w3l[k*64+n]; }
  else if (idx <  98304){ int t=idx- 90112; int n=t/128,k=t%128; v=w3r[k*64+n]; }
  else if (idx < 102400){ int t=idx- 98304; int n=t/64, k=t%64;  v=tcnw[(n*64+k)*2+0]; }
  else if (idx < 106496){ int t=idx-102400; int n=t/64, k=t%64;  v=tcnw[(n*64+k)*2+1]; }
  else if (idx < 110592){ int t=idx-106496; int n=t/64, k=t%64;  v=wq[k*64+n]; }
  else if (idx < 114688){ int t=idx-110592; int n=t/64, k=t%64;  v=wk[k*64+n]; }
  else if (idx < 118784){ int t=idx-114688; int n=t/64, k=t%64;  v=wv[k*64+n]; }
  else if (idx < 122880){ int t=idx-118784; int n=t/64, k=t%64;  v=wo[k*64+n]; }
  else if (idx < 253952){ int t=idx-122880; int kh=t/8192, r=t%8192, n=r/128, k=r%128;
                          v=fc1w[kh*8192 + k*64 + n]; }
  else                  { int t=idx-253952; int kh=t/2048, r=t%2048, n=r/64,  k=r%64;
                          v=(n<24)? fc2w[kh*1536 + k*24 + n] : 0.f; }
  W[idx] = f2bf(v);
}

// ---------------------------------------------------------------------------
// dual GEMM for one SAGE layer (per-wave, 16 rows):
//   accu = h@Wl  -> staged to U(lds);  accv = h@Wr;  accv += A @ u  (K=16 pad 32)
// ---------------------------------------------------------------------------
template<int KC, int NC>
static __device__ __forceinline__ void dual_gemm(
    const unsigned short* __restrict__ A_lds,   // [64][136], rows w*16..
    unsigned short* __restrict__ U,             // [64][136] u-stage
    const unsigned short* __restrict__ Wl,
    const unsigned short* __restrict__ Wr, int wK,
    const unsigned short* __restrict__ AbfW,    // this wave's [16][32] A (bf16)
    int w, int quad, int l15, f32x4* accv)
{
  f32x4 z = {0.f,0.f,0.f,0.f};
  f32x4 accu[NC];
  #pragma unroll
  for (int c=0;c<NC;++c){ accu[c]=z; accv[c]=z; }
  #pragma unroll
  for (int kc=0;kc<KC;++kc){
    bf16x8 a = ld8(A_lds + (w*16+l15)*136 + kc*32 + quad*8);
    #pragma unroll
    for (int c=0;c<NC;++c){
      accu[c] = MFMA16(a, ld8(Wl + (c*16+l15)*wK + kc*32+quad*8), accu[c]);
      accv[c] = MFMA16(a, ld8(Wr + (c*16+l15)*wK + kc*32+quad*8), accv[c]);
    }
  }
  // stage u (C-layout -> LDS)
  #pragma unroll
  for (int c=0;c<NC;++c)
    #pragma unroll
    for (int r=0;r<4;++r)
      U[(w*16+quad*4+r)*136 + c*16+l15] = f2bf(accu[c][r]);
  // accv += A @ u   (A-frag: A[m=l15][k=quad*8+j], zero for k>=16)
  bf16x8 aA = ld8(AbfW + l15*32 + quad*8);
  #pragma unroll
  for (int c=0;c<NC;++c){
    union { unsigned short s[8]; bf16x8 v; } bu;
    #pragma unroll
    for (int j=0;j<8;++j){
      int kr = quad*8+j; if (kr>=16) kr=0;   // A is zero there; value irrelevant
      bu.s[j] = U[(w*16+kr)*136 + c*16+l15];
    }
    accv[c] = MFMA16(aA, bu.v, accv[c]);
  }
}

// ---------------------------------------------------------------------------
// fused GNN + TCN + attention + proj : 1 wg = 4 graphs, 1 wave = 1 graph
// ---------------------------------------------------------------------------
__global__ __launch_bounds__(256) void k_fused(
  const float* __restrict__ x, const int* __restrict__ edst,
  const float* __restrict__ b1, const float* __restrict__ b2,
  const float* __restrict__ b3, const float* __restrict__ tcnb,
  const float* __restrict__ wproj, const float* __restrict__ bproj,
  const unsigned short* __restrict__ ws0, unsigned short* __restrict__ feat)
{
  // LDS pool: U(18432) | H(17408) | V(9216) | Abf(4096) | S0(5120) = 54272 B
  __shared__ alignas(16) unsigned char pool[54272];
  unsigned short* U   = (unsigned short*)(pool);
  unsigned short* H   = (unsigned short*)(pool+18432);
  unsigned short* V   = (unsigned short*)(pool+35840);
  unsigned short* Abf = (unsigned short*)(pool+45056);
  float* S0 = (float*)(pool+49152);

  const int tid = threadIdx.x;
  const int w = tid>>6, lane = tid&63, quad = lane>>4, l15 = lane&15;
  const int gb = blockIdx.x*4 + w;      // graph id
  const int nb = gb*16;                 // first node of graph

  // ---- build normalized adjacency A[d][s] (wave-local) ----
  float* Acnt = S0;           // [4][16][16]
  float* cnt  = S0 + 1024;    // [4][16]
  for (int i=lane;i<256;i+=64) Acnt[w*256+i]=0.f;
  if (lane<16) cnt[w*16+lane]=0.f;
  {
    int d = (edst[gb*64 + lane] - nb) & 15;   // dest local (mask = safety)
    int s = lane>>2;                          // src local = e/4
    atomicAdd(&Acnt[w*256 + d*16 + s], 1.f);
    atomicAdd(&cnt [w*16  + d], 1.f);
  }
  __syncthreads();   // order atomics vs reads (paranoia; all traffic is wave-local)
  for (int i=lane;i<512;i+=64){
    int r=i>>5, kk=i&31;
    float v = 0.f;
    if (kk<16) v = Acnt[w*256 + r*16 + kk] / fmaxf(cnt[w*16+r],1.f);
    Abf[w*512 + i] = f2bf(v);
  }

  // ---- SAGE layer 1: h1 = relu(A@(x@w1l) + x@w1r + b1), K=168 (pad 192) ----
  f32x4 z = {0.f,0.f,0.f,0.f};
  {
    f32x4 accu[8], accv[8];
    #pragma unroll
    for (int c=0;c<8;++c){ accu[c]=z; accv[c]=z; }
    const float* xrow = x + (long long)(nb + l15)*168;
    const unsigned short* Wl = ws0 + O_W1L;
    const unsigned short* Wr = ws0 + O_W1R;
    #pragma unroll
    for (int kc=0;kc<6;++kc){
      int k0 = kc*32 + quad*8;
      int ks = (k0<168)? k0 : 0;    // clamp; wt rows >=168 are zero
      float4 f0 = *(const float4*)(xrow+ks);
      float4 f1 = *(const float4*)(xrow+ks+4);
      union { unsigned short s[8]; bf16x8 v; } au;
      au.s[0]=f2bf(f0.x); au.s[1]=f2bf(f0.y); au.s[2]=f2bf(f0.z); au.s[3]=f2bf(f0.w);
      au.s[4]=f2bf(f1.x); au.s[5]=f2bf(f1.y); au.s[6]=f2bf(f1.z); au.s[7]=f2bf(f1.w);
      bf16x8 a = au.v;
      #pragma unroll
      for (int c=0;c<8;++c){
        accu[c] = MFMA16(a, ld8(Wl + (c*16+l15)*192 + k0), accu[c]);
        accv[c] = MFMA16(a, ld8(Wr + (c*16+l15)*192 + k0), accv[c]);
      }
    }
    #pragma unroll
    for (int c=0;c<8;++c)
      #pragma unroll
      for (int r=0;r<4;++r)
        U[(w*16+quad*4+r)*136 + c*16+l15] = f2bf(accu[c][r]);
    bf16x8 aA = ld8(Abf + w*512 + l15*32 + quad*8);
    #pragma unroll
    for (int c=0;c<8;++c){
      union { unsigned short s[8]; bf16x8 v; } bu;
      #pragma unroll
      for (int j=0;j<8;++j){ int kr=quad*8+j; if (kr>=16) kr=0;
        bu.s[j] = U[(w*16+kr)*136 + c*16+l15]; }
      accv[c] = MFMA16(aA, bu.v, accv[c]);
    }
    #pragma unroll
    for (int c=0;c<8;++c){
      float bb = b1[c*16+l15];
      #pragma unroll
      for (int r=0;r<4;++r)
        H[(w*16+quad*4+r)*136 + c*16+l15] = f2bf(fmaxf(accv[c][r]+bb, 0.f));
    }
  }

  // ---- SAGE layer 2 ----
  {
    f32x4 acc2[8];
    dual_gemm<4,8>(H, U, ws0+O_W2L, ws0+O_W2R, 128, Abf+w*512, w,quad,l15, acc2);
    #pragma unroll
    for (int c=0;c<8;++c){
      float bb = b2[c*16+l15];
      #pragma unroll
      for (int r=0;r<4;++r)
        H[(w*16+quad*4+r)*136 + c*16+l15] = f2bf(fmaxf(acc2[c][r]+bb, 0.f));
    }
  }

  // ---- SAGE layer 3 (no relu) ----
  f32x4 acc3[4];
  dual_gemm<4,4>(H, U, ws0+O_W3L, ws0+O_W3R, 128, Abf+w*512, w,quad,l15, acc3);

  __syncthreads();   // B2: all waves done reading U/H at stride 136; repurpose strides

  unsigned short* X  = U;            // [64][72] h3
  unsigned short* Xs = U + 4608;     // [64][72] shifted h3
  #pragma unroll
  for (int c=0;c<4;++c){
    float bb = b3[c*16+l15];
    #pragma unroll
    for (int r=0;r<4;++r)
      X[(w*16+quad*4+r)*72 + c*16+l15] = f2bf(acc3[c][r]+bb);
  }
  for (int i=lane;i<1024;i+=64){
    int rr=i>>6, cc=i&63;
    Xs[(w*16+rr)*72+cc] = (rr==0)? (unsigned short)0 : X[(w*16+rr-1)*72+cc];
  }

  // ---- TCN: t = relu(Xs@W0 + X@W1 + tcn_b) + X ----
  unsigned short* T = H;             // [64][72]
  {
    f32x4 acct[4] = {z,z,z,z};
    #pragma unroll
    for (int kc=0;kc<2;++kc){
      bf16x8 as_ = ld8(Xs + (w*16+l15)*72 + kc*32+quad*8);
      bf16x8 ax  = ld8(X  + (w*16+l15)*72 + kc*32+quad*8);
      #pragma unroll
      for (int c=0;c<4;++c){
        acct[c] = MFMA16(as_, ld8(ws0+O_T0 + (c*16+l15)*64 + kc*32+quad*8), acct[c]);
        acct[c] = MFMA16(ax,  ld8(ws0+O_T1 + (c*16+l15)*64 + kc*32+quad*8), acct[c]);
      }
    }
    #pragma unroll
    for (int c=0;c<4;++c){
      float tb = tcnb[c*16+l15];
      #pragma unroll
      for (int r=0;r<4;++r){
        int row = w*16+quad*4+r;
        float val = fmaxf(acct[c][r]+tb, 0.f) + bf2f(X[row*72 + c*16+l15]);
        T[row*72 + c*16+l15] = f2bf(val);
      }
    }
  }

  // ---- QKV projections ----
  unsigned short* Q  = U;            // overwrites X  (own-wave bytes)
  unsigned short* Kk = U + 4608;     // overwrites Xs
  unsigned short* Vv = V;
  {
    f32x4 aq[4]={z,z,z,z}, ak[4]={z,z,z,z}, av[4]={z,z,z,z};
    #pragma unroll
    for (int kc=0;kc<2;++kc){
      bf16x8 a = ld8(T + (w*16+l15)*72 + kc*32+quad*8);
      #pragma unroll
      for (int c=0;c<4;++c){
        aq[c] = MFMA16(a, ld8(ws0+O_WQ + (c*16+l15)*64 + kc*32+quad*8), aq[c]);
        ak[c] = MFMA16(a, ld8(ws0+O_WK + (c*16+l15)*64 + kc*32+quad*8), ak[c]);
        av[c] = MFMA16(a, ld8(ws0+O_WV + (c*16+l15)*64 + kc*32+quad*8), av[c]);
      }
    }
    #pragma unroll
    for (int c=0;c<4;++c)
      #pragma unroll
      for (int r=0;r<4;++r){
        int row = w*16+quad*4+r, col = c*16+l15;
        Q [row*72+col] = f2bf(aq[c][r]);
        Kk[row*72+col] = f2bf(ak[c][r]);
        Vv[row*72+col] = f2bf(av[c][r]);
      }
  }

  // ---- attention core: lane = (head=quad, row=l15); softmax fully in-lane ----
  {
    int h=quad, i=l15;
    float qv[16];
    unpack8(Q + (w*16+i)*72 + h*16,     qv);
    unpack8(Q + (w*16+i)*72 + h*16 + 8, qv+8);
    float S[16];
    #pragma unroll
    for (int j=0;j<16;++j){
      float kf[16];
      unpack8(Kk + (w*16+j)*72 + h*16,     kf);
      unpack8(Kk + (w*16+j)*72 + h*16 + 8, kf+8);
      float s=0.f;
      #pragma unroll
      for (int d=0;d<16;++d) s += qv[d]*kf[d];
      S[j] = s*0.25f;                               // 1/sqrt(16)
    }
    float m=S[0];
    #pragma unroll
    for (int j=1;j<16;++j) m = fmaxf(m,S[j]);
    float p[16], sum=0.f;
    #pragma unroll
    for (int j=0;j<16;++j){ p[j]=__expf(S[j]-m); sum+=p[j]; }
    float inv = 1.f/sum;
    float oa[16];
    #pragma unroll
    for (int d=0;d<16;++d) oa[d]=0.f;
    #pragma unroll
    for (int j=0;j<16;++j){
      float vf[16];
      unpack8(Vv + (w*16+j)*72 + h*16,     vf);
      unpack8(Vv + (w*16+j)*72 + h*16 + 8, vf+8);
      float pj = p[j]*inv;
      #pragma unroll
      for (int d=0;d<16;++d) oa[d] += pj*vf[d];
    }
    union { unsigned short s[8]; uint4 u; } o1,o2;
    #pragma unroll
    for (int d=0;d<8;++d){ o1.s[d]=f2bf(oa[d]); o2.s[d]=f2bf(oa[d+8]); }
    unsigned short* orow = Vv + (w*16+i)*72 + h*16;   // o overwrites v (post-read)
    *(uint4*)(orow)   = o1.u;
    *(uint4*)(orow+8) = o2.u;
  }

  // ---- o @ wo, mean over 16 nodes, @ wproj + bproj -> feat ----
  {
    f32x4 ao[4]={z,z,z,z};
    #pragma unroll
    for (int kc=0;kc<2;++kc){
      bf16x8 a = ld8(Vv + (w*16+l15)*72 + kc*32+quad*8);
      #pragma unroll
      for (int c=0;c<4;++c)
        ao[c] = MFMA16(a, ld8(ws0+O_WO + (c*16+l15)*64 + kc*32+quad*8), ao[c]);
    }
    float* part = S0;          // [4][4][64]  (Acnt long dead)
    float* fpre = S0 + 1024;   // [4][64]
    #pragma unroll
    for (int c=0;c<4;++c)
      part[w*256 + quad*64 + c*16+l15] = ao[c][0]+ao[c][1]+ao[c][2]+ao[c][3];
    {
      int col = lane;          // 64 cols, one per lane
      float sm = part[w*256+col] + part[w*256+64+col]
               + part[w*256+128+col] + part[w*256+192+col];
      fpre[w*64+col] = sm * (1.f/16.f);
    }
    float a0 = bproj[lane], a1 = bproj[lane+64];
    for (int c=0;c<64;++c){
      float f = fpre[w*64+c];
      a0 += f * wproj[c*128 + lane];
      a1 += f * wproj[c*128 + lane + 64];
    }
    feat[gb*128 + lane]      = f2bf(a0);
    feat[gb*128 + lane + 64] = f2bf(a1);
  }
}

// ---------------------------------------------------------------------------
// per-variable fc heads: pred[k] = relu(feat@fc1_w[k]+fc1_b[k])@fc2_w[k]+fc2_b[k]
// ---------------------------------------------------------------------------
__global__ __launch_bounds__(256) void k_heads(
  const unsigned short* __restrict__ ws0,
  const float* __restrict__ fc1b, const float* __restrict__ fc2b,
  float* __restrict__ pred)
{
  __shared__ alignas(16) unsigned short hh[64*72];
  const int tid=threadIdx.x, w=tid>>6, lane=tid&63, quad=lane>>4, l15=lane&15;
  const int kh = blockIdx.x>>8, rt = blockIdx.x & 255;
  const int rb = rt*64 + w*16;
  const unsigned short* feat = ws0 + O_FEAT;
  const unsigned short* W1 = ws0 + O_FC1 + kh*8192;
  const unsigned short* W2 = ws0 + O_FC2 + kh*2048;
  f32x4 z={0.f,0.f,0.f,0.f};
  f32x4 acc[4]={z,z,z,z};
  #pragma unroll
  for (int kc=0;kc<4;++kc){
    bf16x8 a = ld8(feat + (rb+l15)*128 + kc*32+quad*8);
    #pragma unroll
    for (int c=0;c<4;++c)
      acc[c] = MFMA16(a, ld8(W1 + (c*16+l15)*128 + kc*32+quad*8), acc[c]);
  }
  #pragma unroll
  for (int c=0;c<4;++c){
    float bb = fc1b[kh*64 + c*16+l15];
    #pragma unroll
    for (int r=0;r<4;++r)
      hh[(w*16+quad*4+r)*72 + c*16+l15] = f2bf(fmaxf(acc[c][r]+bb,0.f));
  }
  f32x4 acc2[2]={z,z};
  #pragma unroll
  for (int kc=0;kc<2;++kc){
    bf16x8 a = ld8(hh + (w*16+l15)*72 + kc*32+quad*8);
    #pragma unroll
    for (int c=0;c<2;++c)
      acc2[c] = MFMA16(a, ld8(W2 + (c*16+l15)*64 + kc*32+quad*8), acc2[c]);
  }
  #pragma unroll
  for (int c=0;c<2;++c){
    int col = c*16+l15;
    if (col < 24){
      float bb = fc2b[kh*24+col];
      #pragma unroll
      for (int r=0;r<4;++r){
        int row = rb + quad*4 + r;
        pred[(size_t)kh*16384*24 + (size_t)row*24 + col] = acc2[c][r] + bb;
      }
    }
  }
}

// yb output = y.reshape -> exact copy
__global__ __launch_bounds__(256) void k_copy(const float4* __restrict__ y,
                                              float4* __restrict__ o)
{
  int i = blockIdx.x*256 + threadIdx.x;   // exactly 1572864 elements
  o[i] = y[i];
}

// ---------------------------------------------------------------------------
extern "C" void kernel_launch(void* const* d_in, const int* in_sizes, int n_in,
                              void* d_out, int out_size, void* d_ws, size_t ws_size,
                              hipStream_t stream) {
  const float* x    = (const float*)d_in[0];
  const float* y    = (const float*)d_in[1];
  const int*   ei   = (const int*)d_in[2];      // [2][E], int32 (jax default)
  const float* w1l  = (const float*)d_in[4];
  const float* w1r  = (const float*)d_in[5];
  const float* b1   = (const float*)d_in[6];
  const float* w2l  = (const float*)d_in[7];
  const float* w2r  = (const float*)d_in[8];
  const float* b2   = (const float*)d_in[9];
  const float* w3l  = (const float*)d_in[10];
  const float* w3r  = (const float*)d_in[11];
  const float* b3   = (const float*)d_in[12];
  const float* tcnw = (const float*)d_in[13];
  const float* tcnb = (const float*)d_in[14];
  const float* wq   = (const float*)d_in[15];
  const float* wk   = (const float*)d_in[16];
  const float* wv   = (const float*)d_in[17];
  const float* wo   = (const float*)d_in[18];
  const float* wpr  = (const float*)d_in[19];
  const float* bpr  = (const float*)d_in[20];
  const float* fc1w = (const float*)d_in[21];
  const float* fc1b = (const float*)d_in[22];
  const float* fc2w = (const float*)d_in[23];
  const float* fc2b = (const float*)d_in[24];

  unsigned short* W = (unsigned short*)d_ws;
  float* out = (float*)d_out;

  k_prep<<<1120, 256, 0, stream>>>(w1l,w1r,w2l,w2r,w3l,w3r,tcnw,wq,wk,wv,wo,fc1w,fc2w,W);
  k_fused<<<NGR/4, 256, 0, stream>>>(x, ei + EDGES, b1,b2,b3,tcnb,wpr,bpr, W, W + O_FEAT);
  k_heads<<<16*256, 256, 0, stream>>>(W, fc1b, fc2b, out);
  k_copy<<<6144, 256, 0, stream>>>((const float4*)y, (float4*)(out + PRED_ELEMS));
}

// Round 2
// 812.940 us; speedup vs baseline: 1.2577x; 1.2577x over previous
//
#include <hip/hip_runtime.h>
#include <cstdint>
#include <cstddef>

// ---------------------------------------------------------------------------
// SSTAFormer round 2: occupancy + chain-shortening rewrite.
//   - 1 wave = 1 graph (16 nodes), 4 graphs per 256-thread workgroup.
//   - Per-wave LDS arena 9472 B (4 x 9472 = 37888 B/wg -> 4 wg/CU by LDS).
//   - __launch_bounds__(256,4) -> VGPR <= 128 -> 4 waves/SIMD.
//   - No __syncthreads anywhere in k_fused (all LDS traffic wave-private;
//     __threadfence_block() at region-overlay boundaries as compiler fences).
//   - u^T staging: A@u B-frags are ds_read_b128 (was 8x ds_read_u16).
//   - MFMA attention (S=QK^T, PV) + shfl softmax (was ~500 VALU in-lane).
// ---------------------------------------------------------------------------

typedef __attribute__((ext_vector_type(8))) __bf16 bf16x8;
typedef __attribute__((ext_vector_type(4))) float  f32x4;

#define MFMA16(a,b,c) __builtin_amdgcn_mfma_f32_16x16x32_bf16((a),(b),(c),0,0,0)
#define FENCE() __threadfence_block()

#define NGR    16384
#define EDGES  1048576
#define PRED_ELEMS (16*16384*24)

// workspace layout in ushort units (same as round 1; k_prep unchanged)
#define O_W1L 0               // [128][192]
#define O_W1R 24576
#define O_W2L 49152           // [128][128]
#define O_W2R 65536
#define O_W3L 81920           // [64][128]
#define O_W3R 90112
#define O_T0  98304           // [64 co][64 ci]  (tcn_w[...,0])
#define O_T1  102400
#define O_WQ  106496          // [64][64]
#define O_WK  110592
#define O_WV  114688
#define O_WO  118784
#define O_FC1 122880          // 16 x [64][128]
#define O_FC2 253952          // 16 x [32][64]
#define O_FEAT 286720         // [16384][128] bf16
#define PREP_TOT 286720

static __device__ __forceinline__ unsigned short f2bf(float f){
  unsigned int u = __builtin_bit_cast(unsigned int, f);
  u += 0x7FFFu + ((u >> 16) & 1u);            // RNE
  return (unsigned short)(u >> 16);
}
static __device__ __forceinline__ float bf2f(unsigned short h){
  return __builtin_bit_cast(float, (unsigned int)h << 16);
}
static __device__ __forceinline__ bf16x8 ld8(const unsigned short* p){
  return __builtin_bit_cast(bf16x8, *(const uint4*)p);   // 16B aligned by construction
}
static __device__ __forceinline__ bf16x8 zero8(){
  uint4 u = make_uint4(0u,0u,0u,0u);
  return __builtin_bit_cast(bf16x8, u);
}
static __device__ __forceinline__ ushort4 pack4(f32x4 v){
  ushort4 p; p.x=f2bf(v[0]); p.y=f2bf(v[1]); p.z=f2bf(v[2]); p.w=f2bf(v[3]); return p;
}
// A-fragment from global fp32 x row (K padded 168->192, W rows >=168 are zero)
static __device__ __forceinline__ bf16x8 xfrag(const float* __restrict__ xrow, int k0){
  int ks = (k0 < 168) ? k0 : 0;          // clamped lanes multiply zero W rows
  float4 f0 = *(const float4*)(xrow + ks);
  float4 f1 = *(const float4*)(xrow + ks + 4);
  union { unsigned short s[8]; bf16x8 v; } u;
  u.s[0]=f2bf(f0.x); u.s[1]=f2bf(f0.y); u.s[2]=f2bf(f0.z); u.s[3]=f2bf(f0.w);
  u.s[4]=f2bf(f1.x); u.s[5]=f2bf(f1.y); u.s[6]=f2bf(f1.z); u.s[7]=f2bf(f1.w);
  return u.v;
}

// ---------------------------------------------------------------------------
// weight prep (unchanged from round 1, verified correct)
// ---------------------------------------------------------------------------
__global__ __launch_bounds__(256) void k_prep(
  const float* __restrict__ w1l, const float* __restrict__ w1r,
  const float* __restrict__ w2l, const float* __restrict__ w2r,
  const float* __restrict__ w3l, const float* __restrict__ w3r,
  const float* __restrict__ tcnw,
  const float* __restrict__ wq, const float* __restrict__ wk,
  const float* __restrict__ wv, const float* __restrict__ wo,
  const float* __restrict__ fc1w, const float* __restrict__ fc2w,
  unsigned short* __restrict__ W)
{
  int idx = blockIdx.x*256 + threadIdx.x;
  if (idx >= PREP_TOT) return;
  float v;
  if      (idx <  24576){ int t=idx;        int n=t/192,k=t%192; v=(k<168)? w1l[k*128+n]:0.f; }
  else if (idx <  49152){ int t=idx- 24576; int n=t/192,k=t%192; v=(k<168)? w1r[k*128+n]:0.f; }
  else if (idx <  65536){ int t=idx- 49152; int n=t/128,k=t%128; v=w2l[k*128+n]; }
  else if (idx <  81920){ int t=idx- 65536; int n=t/128,k=t%128; v=w2r[k*128+n]; }
  else if (idx <  90112){ int t=idx- 81920; int n=t/128,k=t%128; v=w3l[k*64+n]; }
  else if (idx <  98304){ int t=idx- 90112; int n=t/128,k=t%128; v=w3r[k*64+n]; }
  else if (idx < 102400){ int t=idx- 98304; int n=t/64, k=t%64;  v=tcnw[(n*64+k)*2+0]; }
  else if (idx < 106496){ int t=idx-102400; int n=t/64, k=t%64;  v=tcnw[(n*64+k)*2+1]; }
  else if (idx < 110592){ int t=idx-106496; int n=t/64, k=t%64;  v=wq[k*64+n]; }
  else if (idx < 114688){ int t=idx-110592; int n=t/64, k=t%64;  v=wk[k*64+n]; }
  else if (idx < 118784){ int t=idx-114688; int n=t/64, k=t%64;  v=wv[k*64+n]; }
  else if (idx < 122880){ int t=idx-118784; int n=t/64, k=t%64;  v=wo[k*64+n]; }
  else if (idx < 253952){ int t=idx-122880; int kh=t/8192, r=t%8192, n=r/128, k=r%128;
                          v=fc1w[kh*8192 + k*64 + n]; }
  else                  { int t=idx-253952; int kh=t/2048, r=t%2048, n=r/64,  k=r%64;
                          v=(n<24)? fc2w[kh*1536 + k*24 + n] : 0.f; }
  W[idx] = f2bf(v);
}

// ---------------------------------------------------------------------------
// SAGE core (layers 2,3): two-pass (halves live accumulators for VGPR<=128).
//   pass1: u = h@Wl -> stored transposed UT[col][node] via ds_write_b64
//   pass2: accv = h@Wr + A@u   (A-frag aA has exact zeros for k>=16, so the
//          UT overflow reads at quad>=2 are multiplied by 0)
// ---------------------------------------------------------------------------
template<int NC>
static __device__ __forceinline__ void sage_core(
    const unsigned short* __restrict__ h,     // this wave's [16][136]
    unsigned short* __restrict__ UT,          // this wave's [128][16]
    bf16x8 aA,
    const unsigned short* __restrict__ Wl,
    const unsigned short* __restrict__ Wr,
    int quad, int l15, f32x4* accv)
{
  f32x4 z = {0.f,0.f,0.f,0.f};
  {
    f32x4 accu[NC];
    #pragma unroll
    for (int c=0;c<NC;++c) accu[c]=z;
    #pragma unroll
    for (int kc=0;kc<4;++kc){
      bf16x8 a = ld8(h + l15*136 + kc*32 + quad*8);
      #pragma unroll
      for (int c=0;c<NC;++c)
        accu[c] = MFMA16(a, ld8(Wl + (c*16+l15)*128 + kc*32+quad*8), accu[c]);
    }
    #pragma unroll
    for (int c=0;c<NC;++c)
      *(ushort4*)(UT + (c*16+l15)*16 + quad*4) = pack4(accu[c]);
  }
  FENCE();
  #pragma unroll
  for (int c=0;c<NC;++c) accv[c]=z;
  #pragma unroll
  for (int kc=0;kc<4;++kc){
    bf16x8 a = ld8(h + l15*136 + kc*32 + quad*8);
    #pragma unroll
    for (int c=0;c<NC;++c)
      accv[c] = MFMA16(a, ld8(Wr + (c*16+l15)*128 + kc*32+quad*8), accv[c]);
  }
  #pragma unroll
  for (int c=0;c<NC;++c)
    accv[c] = MFMA16(aA, ld8(UT + (c*16+l15)*16 + quad*8), accv[c]);
}

// ---------------------------------------------------------------------------
// fused GNN + TCN + attention + proj : 1 wg = 4 graphs, 1 wave = 1 graph
// ---------------------------------------------------------------------------
__global__ __launch_bounds__(256,4) void k_fused(
  const float* __restrict__ x, const int* __restrict__ edst,
  const float* __restrict__ b1, const float* __restrict__ b2,
  const float* __restrict__ b3, const float* __restrict__ tcnb,
  const float* __restrict__ wproj, const float* __restrict__ bproj,
  const unsigned short* __restrict__ ws0, unsigned short* __restrict__ feat)
{
  __shared__ alignas(16) unsigned char pool[4*9472];
  const int tid=threadIdx.x, w=tid>>6, lane=tid&63, quad=lane>>4, l15=lane&15;
  unsigned short* AR = (unsigned short*)(pool + w*9472);
  const int gb = blockIdx.x*4 + w, nb = gb*16;

  // phase A regions (ushort offsets in arena)
  unsigned short* Hb  = AR;          // [16][136]  (0..2176)
  unsigned short* UT  = AR + 2176;   // [128][16]  (2176..4224)
  unsigned short* Abf = AR + 4224;   // [16][32]   (4224..4736), cols 16.. zero
  // phase B overlays (all within-wave, ordered by program order + fences)
  unsigned short* X   = AR;          // [16][72]   (0..1152)    over Hb head
  unsigned short* T   = AR + 1152;   // [16][72]   (1152..2304) over Hb tail/UT
  unsigned short* Q   = AR + 2304;   // [16][72]   (2304..3456) over UT
  unsigned short* Kr  = AR;          // [16][72]   (0..1152)    over X (dead)
  unsigned short* VT  = AR + 1152;   // [64][16]   (1152..2176) over T head (post-read)
  unsigned short* Pb  = AR + 3456;   // [4][16][16](3456..4480) over UT tail/Abf
  unsigned short* Ost = AR + 2176;   // [16][72]   (2176..3328) over Q (dead)

  const bf16x8 Z = zero8();
  const f32x4  z = {0.f,0.f,0.f,0.f};

  // ---- adjacency via shfl (lane = (quad, l15): row d=l15, cols s=quad*4+ss) ----
  int dloc = edst[gb*64 + lane] & 15;
  float c4[4]; float csum = 0.f;
  #pragma unroll
  for (int ss=0; ss<4; ++ss){
    int s = quad*4 + ss; int cc = 0;
    #pragma unroll
    for (int k=0;k<4;++k) cc += (__shfl(dloc, s*4+k, 64) == l15) ? 1 : 0;
    c4[ss] = (float)cc; csum += (float)cc;
  }
  csum += __shfl_xor(csum, 16, 64);
  csum += __shfl_xor(csum, 32, 64);
  float ainv = 1.f / fmaxf(csum, 1.f);
  ushort4 pkA;
  pkA.x=f2bf(c4[0]*ainv); pkA.y=f2bf(c4[1]*ainv);
  pkA.z=f2bf(c4[2]*ainv); pkA.w=f2bf(c4[3]*ainv);
  *(ushort4*)(Abf + l15*32 + quad*4) = pkA;
  ushort4 zz; zz.x=0; zz.y=0; zz.z=0; zz.w=0;
  *(ushort4*)(Abf + l15*32 + 16 + quad*4) = zz;        // exact zeros for k>=16
  FENCE();
  bf16x8 aA = ld8(Abf + l15*32 + quad*8);              // held in regs for all layers

  // ---- SAGE layer 1 (K=168 pad 192, A-frags straight from global x) ----
  const float* xrow = x + (size_t)(nb + l15) * 168;
  {
    f32x4 accu[8];
    #pragma unroll
    for (int c=0;c<8;++c) accu[c]=z;
    #pragma unroll
    for (int kc=0;kc<6;++kc){
      bf16x8 a = xfrag(xrow, kc*32 + quad*8);
      #pragma unroll
      for (int c=0;c<8;++c)
        accu[c] = MFMA16(a, ld8(ws0+O_W1L + (c*16+l15)*192 + kc*32+quad*8), accu[c]);
    }
    #pragma unroll
    for (int c=0;c<8;++c)
      *(ushort4*)(UT + (c*16+l15)*16 + quad*4) = pack4(accu[c]);
  }
  FENCE();
  {
    f32x4 accv[8];
    #pragma unroll
    for (int c=0;c<8;++c) accv[c]=z;
    #pragma unroll
    for (int kc=0;kc<6;++kc){
      bf16x8 a = xfrag(xrow, kc*32 + quad*8);
      #pragma unroll
      for (int c=0;c<8;++c)
        accv[c] = MFMA16(a, ld8(ws0+O_W1R + (c*16+l15)*192 + kc*32+quad*8), accv[c]);
    }
    #pragma unroll
    for (int c=0;c<8;++c)
      accv[c] = MFMA16(aA, ld8(UT + (c*16+l15)*16 + quad*8), accv[c]);
    #pragma unroll
    for (int c=0;c<8;++c){
      float bb = b1[c*16+l15];
      #pragma unroll
      for (int r=0;r<4;++r)
        Hb[(quad*4+r)*136 + c*16+l15] = f2bf(fmaxf(accv[c][r]+bb, 0.f));
    }
  }
  FENCE();

  // ---- SAGE layer 2 ----
  {
    f32x4 acc2[8];
    sage_core<8>(Hb, UT, aA, ws0+O_W2L, ws0+O_W2R, quad, l15, acc2);
    #pragma unroll
    for (int c=0;c<8;++c){
      float bb = b2[c*16+l15];
      #pragma unroll
      for (int r=0;r<4;++r)
        Hb[(quad*4+r)*136 + c*16+l15] = f2bf(fmaxf(acc2[c][r]+bb, 0.f));
    }
  }
  FENCE();

  // ---- SAGE layer 3 (no relu) -> X, residual values kept in regs ----
  float xres[4][4];
  {
    f32x4 acc3[4];
    sage_core<4>(Hb, UT, aA, ws0+O_W3L, ws0+O_W3R, quad, l15, acc3);
    #pragma unroll
    for (int c=0;c<4;++c){
      float bb = b3[c*16+l15];
      #pragma unroll
      for (int r=0;r<4;++r){
        unsigned short hv = f2bf(acc3[c][r]+bb);
        xres[c][r] = bf2f(hv);                     // exact value seen by residual
        X[(quad*4+r)*72 + c*16+l15] = hv;
      }
    }
  }
  FENCE();

  // ---- TCN: t = relu(Xshift@W0 + X@W1 + tcn_b) + X  (shift = row-1 read) ----
  {
    f32x4 acct[4] = {z,z,z,z};
    #pragma unroll
    for (int kc=0;kc<2;++kc){
      bf16x8 ax  = ld8(X + l15*72 + kc*32+quad*8);
      bf16x8 as_ = (l15>0) ? ld8(X + (l15-1)*72 + kc*32+quad*8) : Z;
      #pragma unroll
      for (int c=0;c<4;++c){
        acct[c] = MFMA16(as_, ld8(ws0+O_T0 + (c*16+l15)*64 + kc*32+quad*8), acct[c]);
        acct[c] = MFMA16(ax,  ld8(ws0+O_T1 + (c*16+l15)*64 + kc*32+quad*8), acct[c]);
      }
    }
    #pragma unroll
    for (int c=0;c<4;++c){
      float tb = tcnb[c*16+l15];
      #pragma unroll
      for (int r=0;r<4;++r)
        T[(quad*4+r)*72 + c*16+l15] = f2bf(fmaxf(acct[c][r]+tb, 0.f) + xres[c][r]);
    }
  }
  FENCE();

  // ---- QKV: Q,K row-major; V transposed (for PV B-frags) ----
  {
    f32x4 aq[4]={z,z,z,z}, ak[4]={z,z,z,z}, av[4]={z,z,z,z};
    #pragma unroll
    for (int kc=0;kc<2;++kc){
      bf16x8 a = ld8(T + l15*72 + kc*32+quad*8);
      #pragma unroll
      for (int c=0;c<4;++c){
        aq[c] = MFMA16(a, ld8(ws0+O_WQ + (c*16+l15)*64 + kc*32+quad*8), aq[c]);
        ak[c] = MFMA16(a, ld8(ws0+O_WK + (c*16+l15)*64 + kc*32+quad*8), ak[c]);
        av[c] = MFMA16(a, ld8(ws0+O_WV + (c*16+l15)*64 + kc*32+quad*8), av[c]);
      }
    }
    #pragma unroll
    for (int c=0;c<4;++c){
      #pragma unroll
      for (int r=0;r<4;++r){
        int row = quad*4+r, col = c*16+l15;
        Q [row*72+col] = f2bf(aq[c][r]);
        Kr[row*72+col] = f2bf(ak[c][r]);
      }
      *(ushort4*)(VT + (c*16+l15)*16 + quad*4) = pack4(av[c]);   // V^T[col][node]
    }
  }
  FENCE();

  // ---- S = (Q K^T)/4 per head via MFMA; softmax across l15 lanes -> Pb ----
  {
    bool hv = (quad < 2);                    // K=16 padded to 32: upper half zero
    f32x4 accS[4];
    #pragma unroll
    for (int h=0;h<4;++h){
      bf16x8 aQ = hv ? ld8(Q  + l15*72 + h*16 + quad*8) : Z;
      bf16x8 bK = hv ? ld8(Kr + l15*72 + h*16 + quad*8) : Z;
      accS[h] = MFMA16(aQ, bK, z);
    }
    #pragma unroll
    for (int h=0;h<4;++h){
      #pragma unroll
      for (int r=0;r<4;++r){
        float s = accS[h][r]*0.25f;
        float m = s;
        m = fmaxf(m, __shfl_xor(m,1,64));
        m = fmaxf(m, __shfl_xor(m,2,64));
        m = fmaxf(m, __shfl_xor(m,4,64));
        m = fmaxf(m, __shfl_xor(m,8,64));
        float p = __expf(s-m);
        float su = p;
        su += __shfl_xor(su,1,64);
        su += __shfl_xor(su,2,64);
        su += __shfl_xor(su,4,64);
        su += __shfl_xor(su,8,64);
        Pb[(h*16 + quad*4 + r)*16 + l15] = f2bf(p/su);
      }
    }
  }
  FENCE();

  // ---- O = P@V per head -> Ost rows ----
  {
    bool hv = (quad < 2);
    #pragma unroll
    for (int h=0;h<4;++h){
      bf16x8 aP = hv ? ld8(Pb + (h*16+l15)*16 + quad*8) : Z;
      bf16x8 bV = hv ? ld8(VT + (h*16+l15)*16 + quad*8) : Z;
      f32x4 o = MFMA16(aP, bV, z);
      #pragma unroll
      for (int r=0;r<4;++r)
        Ost[(quad*4+r)*72 + h*16+l15] = f2bf(o[r]);
    }
  }
  FENCE();

  // ---- o @ wo, mean over 16 nodes, @ wproj + bproj -> feat ----
  {
    f32x4 ao[4] = {z,z,z,z};
    #pragma unroll
    for (int kc=0;kc<2;++kc){
      bf16x8 a = ld8(Ost + l15*72 + kc*32+quad*8);
      #pragma unroll
      for (int c=0;c<4;++c)
        ao[c] = MFMA16(a, ld8(ws0+O_WO + (c*16+l15)*64 + kc*32+quad*8), ao[c]);
    }
    float* part = (float*)AR;        // [4 quads][64 cols]  over Kr (dead)
    float* fpre = part + 256;        // [64]
    #pragma unroll
    for (int c=0;c<4;++c)
      part[quad*64 + c*16+l15] = ao[c][0]+ao[c][1]+ao[c][2]+ao[c][3];
    FENCE();
    float sm = part[lane] + part[64+lane] + part[128+lane] + part[192+lane];
    fpre[lane] = sm * (1.f/16.f);
    FENCE();
    float a0 = bproj[lane], a1 = bproj[lane+64];
    for (int c2=0;c2<64;++c2){
      float f = fpre[c2];
      a0 += f * wproj[c2*128 + lane];
      a1 += f * wproj[c2*128 + lane + 64];
    }
    feat[gb*128 + lane]      = f2bf(a0);
    feat[gb*128 + lane + 64] = f2bf(a1);
  }
}

// ---------------------------------------------------------------------------
// per-variable fc heads: 1 wave = one (kh, 16-row tile); 16384 waves total
// ---------------------------------------------------------------------------
__global__ __launch_bounds__(256,6) void k_heads(
  const unsigned short* __restrict__ ws0,
  const float* __restrict__ fc1b, const float* __restrict__ fc2b,
  float* __restrict__ pred)
{
  __shared__ alignas(16) unsigned short hh[4*1152];   // per-wave [16][72]
  const int tid=threadIdx.x, w=tid>>6, lane=tid&63, quad=lane>>4, l15=lane&15;
  const int Wv = blockIdx.x*4 + w;          // 0..16383
  const int kh = Wv & 15, tile = Wv >> 4;
  const int rb = tile*16;
  unsigned short* hw = hh + w*1152;
  const unsigned short* featg = ws0 + O_FEAT;
  const unsigned short* W1 = ws0 + O_FC1 + kh*8192;
  const unsigned short* W2 = ws0 + O_FC2 + kh*2048;
  f32x4 z = {0.f,0.f,0.f,0.f};
  f32x4 acc[4] = {z,z,z,z};
  #pragma unroll
  for (int kc=0;kc<4;++kc){
    bf16x8 a = ld8(featg + (size_t)(rb+l15)*128 + kc*32+quad*8);
    #pragma unroll
    for (int c=0;c<4;++c)
      acc[c] = MFMA16(a, ld8(W1 + (c*16+l15)*128 + kc*32+quad*8), acc[c]);
  }
  #pragma unroll
  for (int c=0;c<4;++c){
    float bb = fc1b[kh*64 + c*16+l15];
    #pragma unroll
    for (int r=0;r<4;++r)
      hw[(quad*4+r)*72 + c*16+l15] = f2bf(fmaxf(acc[c][r]+bb, 0.f));
  }
  __threadfence_block();
  f32x4 acc2[2] = {z,z};
  #pragma unroll
  for (int kc=0;kc<2;++kc){
    bf16x8 a = ld8(hw + l15*72 + kc*32+quad*8);
    #pragma unroll
    for (int c=0;c<2;++c)
      acc2[c] = MFMA16(a, ld8(W2 + (c*16+l15)*64 + kc*32+quad*8), acc2[c]);
  }
  #pragma unroll
  for (int c=0;c<2;++c){
    int col = c*16+l15;
    if (col < 24){
      float bb = fc2b[kh*24+col];
      #pragma unroll
      for (int r=0;r<4;++r)
        pred[(size_t)kh*393216 + (size_t)(rb+quad*4+r)*24 + col] = acc2[c][r] + bb;
    }
  }
}

// yb output = y.reshape -> exact copy
__global__ __launch_bounds__(256) void k_copy(const float4* __restrict__ y,
                                              float4* __restrict__ o)
{
  int i = blockIdx.x*256 + threadIdx.x;   // exactly 1572864 float4s
  o[i] = y[i];
}

// ---------------------------------------------------------------------------
extern "C" void kernel_launch(void* const* d_in, const int* in_sizes, int n_in,
                              void* d_out, int out_size, void* d_ws, size_t ws_size,
                              hipStream_t stream) {
  const float* x    = (const float*)d_in[0];
  const float* y    = (const float*)d_in[1];
  const int*   ei   = (const int*)d_in[2];
  const float* w1l  = (const float*)d_in[4];
  const float* w1r  = (const float*)d_in[5];
  const float* b1   = (const float*)d_in[6];
  const float* w2l  = (const float*)d_in[7];
  const float* w2r  = (const float*)d_in[8];
  const float* b2   = (const float*)d_in[9];
  const float* w3l  = (const float*)d_in[10];
  const float* w3r  = (const float*)d_in[11];
  const float* b3   = (const float*)d_in[12];
  const float* tcnw = (const float*)d_in[13];
  const float* tcnb = (const float*)d_in[14];
  const float* wq   = (const float*)d_in[15];
  const float* wk   = (const float*)d_in[16];
  const float* wv   = (const float*)d_in[17];
  const float* wo   = (const float*)d_in[18];
  const float* wpr  = (const float*)d_in[19];
  const float* bpr  = (const float*)d_in[20];
  const float* fc1w = (const float*)d_in[21];
  const float* fc1b = (const float*)d_in[22];
  const float* fc2w = (const float*)d_in[23];
  const float* fc2b = (const float*)d_in[24];

  unsigned short* W = (unsigned short*)d_ws;
  float* out = (float*)d_out;

  k_prep<<<1120, 256, 0, stream>>>(w1l,w1r,w2l,w2r,w3l,w3r,tcnw,wq,wk,wv,wo,fc1w,fc2w,W);
  k_fused<<<NGR/4, 256, 0, stream>>>(x, ei + EDGES, b1,b2,b3,tcnb,wpr,bpr, W, W + O_FEAT);
  k_heads<<<4096, 256, 0, stream>>>(W, fc1b, fc2b, out);
  k_copy<<<6144, 256, 0, stream>>>((const float4*)y, (float4*)(out + PRED_ELEMS));
}